// Round 12
// baseline (51.938 us; speedup 1.0000x reference)
//
#include <hip/hip_runtime.h>

typedef __attribute__((ext_vector_type(4))) float f32x4;
typedef __attribute__((ext_vector_type(8))) _Float16 f16x8;
typedef __attribute__((ext_vector_type(4))) unsigned short u16x4;

#define NB 8
#define LLEN 512
#define DD 768
#define MW 12
#define HH 384
#define TT (NB * LLEN)      // 4096 tokens
#define SS (LLEN * MW)      // 6144 spans per batch
#define RB 528              // rows per batch in X/R (513 used: t=-1..511, rest pad)
#define MX (NB * RB)        // 4224 GEMM rows

#define PREPX_BLOCKS ((MX * 192) / 256)   // 3168
#define PREPW_BLOCKS ((DD * 192) / 256)   // 576
#define PREP_BLOCKS (PREPX_BLOCKS + PREPW_BLOCKS)

// ---------- helpers ----------
__device__ __forceinline__ unsigned short f2h(float x) {
  _Float16 h = (_Float16)x;               // RNE
  return __builtin_bit_cast(unsigned short, h);
}
__device__ __forceinline__ float h2f(unsigned short u) {
  return (float)__builtin_bit_cast(_Float16, u);
}
__device__ __forceinline__ void gload_lds16(const void* g, void* l) {
  __builtin_amdgcn_global_load_lds(
      (const __attribute__((address_space(1))) unsigned int*)g,
      (__attribute__((address_space(3))) unsigned int*)l, 16, 0, 0);
}

// ---------- prep ----------
// X[r][0:384]   = fwd[b][t]      (ss if t==-1),  r = b*RB + (t+1)
// X[r][384:768] = bwd[b][t+1]    (es if t>=511)
// Wp[e][k] = fp16(W[e][k])   (B^T layout, K contiguous)
__global__ __launch_bounds__(256) void prep_k(const float* __restrict__ h,
                                              const float* __restrict__ W,
                                              const float* __restrict__ ss,
                                              const float* __restrict__ es,
                                              unsigned short* __restrict__ X,
                                              unsigned short* __restrict__ Wp) {
  int bid = blockIdx.x;
  if (bid < PREPX_BLOCKS) {
    int idx = bid * 256 + threadIdx.x;        // over MX*192 u16x4 chunks
    int r = idx / 192;
    int c = (idx - r * 192) * 4;
    int b = r / RB;
    int t = r - b * RB - 1;                   // -1..526
    const float* src;
    if (c < HH) {
      src = (t == -1) ? (ss + c) : (h + ((size_t)b * LLEN + min(t, LLEN - 1)) * DD + c);
    } else {
      src = (t >= LLEN - 1) ? (es + (c - HH))
                            : (h + ((size_t)b * LLEN + (t + 1)) * DD + c);
    }
    f32x4 f = *(const f32x4*)src;
    u16x4 v;
#pragma unroll
    for (int j = 0; j < 4; ++j) v[j] = f2h(f[j]);
    *(u16x4*)(X + (size_t)r * DD + c) = v;
  } else {
    int idx = (bid - PREPX_BLOCKS) * 256 + threadIdx.x;  // over DD*192 chunks
    int e = idx / 192;
    int c = (idx - e * 192) * 4;
    f32x4 f = *(const f32x4*)(W + (size_t)e * DD + c);
    u16x4 v;
#pragma unroll
    for (int j = 0; j < 4; ++j) v[j] = f2h(f[j]);
    *(u16x4*)(Wp + (size_t)e * DD + c) = v;
  }
}

// ---------- fp16 GEMM: R[MX][DD] = X[MX][DD] * Wp^T[DD][DD], R fp16 ----------
// BM=64, BN=96, K=768 (12 kc-iters of 64). Grid 528 = 66 m-panels x 8 n-cols
// = 2.06 blocks/CU. Bijective XCD chunking: XCD x gets ~8.25 consecutive
// m-panels (A L2-local; Wp 1.2 MB L2-resident everywhere).
__global__ __launch_bounds__(256) void gemm_k(const unsigned short* __restrict__ X,
                                              const unsigned short* __restrict__ Wp,
                                              unsigned short* __restrict__ R) {
  __shared__ unsigned short As[64 * 64];    // 8 KB
  __shared__ unsigned short Bs[96 * 64];    // 12 KB

  const int bid = blockIdx.x;
  const int sw = (bid & 7) * 66 + (bid >> 3);   // bijective: 528 = 8*66
  const int mp = sw >> 3, nc = sw & 7;
  const int r0 = mp * 64;
  const int c0 = nc * 96;

  const int tid = threadIdx.x;
  const int lane = tid & 63;
  const int w = tid >> 6;
  const int wr = w >> 1, wc = w & 1;        // 2x2 waves -> each 32x48
  const int l16 = lane & 15, l4 = lane >> 4;
  const char* Xb = (const char*)X;
  const char* Wb = (const char*)Wp;

  f32x4 acc[2][3] = {};

  for (int kc = 0; kc < DD; kc += 64) {
#pragma unroll
    for (int r = 0; r < 2; ++r) {           // A: 64 rows x 128 B
      int o = (r * 256 + tid) * 16;
      int rr = o >> 7, colb = o & 127;
      gload_lds16(Xb + ((size_t)(r0 + rr) * DD + kc) * 2 + colb, (char*)As + o);
    }
#pragma unroll
    for (int r = 0; r < 3; ++r) {           // B: 96 rows x 128 B
      int o = (r * 256 + tid) * 16;
      int rr = o >> 7, colb = o & 127;
      gload_lds16(Wb + ((size_t)(c0 + rr) * DD + kc) * 2 + colb, (char*)Bs + o);
    }
    __syncthreads();

    f16x8 af[2][2], bf[2][3];
#pragma unroll
    for (int ks = 0; ks < 2; ++ks)
#pragma unroll
      for (int m = 0; m < 2; ++m)
        af[ks][m] = *(const f16x8*)&As[(wr * 32 + m * 16 + l16) * 64 + ks * 32 + l4 * 8];
#pragma unroll
    for (int ks = 0; ks < 2; ++ks)
#pragma unroll
      for (int n = 0; n < 3; ++n)
        bf[ks][n] = *(const f16x8*)&Bs[(wc * 48 + n * 16 + l16) * 64 + ks * 32 + l4 * 8];

#pragma unroll
    for (int m = 0; m < 2; ++m)
#pragma unroll
      for (int n = 0; n < 3; ++n) {
        acc[m][n] = __builtin_amdgcn_mfma_f32_16x16x32_f16(af[0][m], bf[0][n], acc[m][n], 0, 0, 0);
        acc[m][n] = __builtin_amdgcn_mfma_f32_16x16x32_f16(af[1][m], bf[1][n], acc[m][n], 0, 0, 0);
      }
    __syncthreads();
  }

  // epilogue: D row=(lane>>4)*4+reg, col=lane&15; store fp16
#pragma unroll
  for (int m = 0; m < 2; ++m) {
    int grow = r0 + wr * 32 + m * 16 + l4 * 4;
#pragma unroll
    for (int n = 0; n < 3; ++n) {
      int gcol = c0 + wc * 48 + n * 16 + l16;
#pragma unroll
      for (int r = 0; r < 4; ++r)
        R[(size_t)(grow + r) * DD + gcol] = f2h(acc[m][n][r]);
    }
  }
}

// ---------- assembly: out[b,s] = relu(R[end] - R[start-1] + bias) ----------
// One block per token (XCD-chunked), 12 spans each; 2 branchless gathers per
// output row (R row for t stored at b*RB + t + 1; rows 0..512 used).
__global__ __launch_bounds__(192) void assemble_k(const int* __restrict__ span,
                                                  const unsigned short* __restrict__ R,
                                                  const float* __restrict__ bias,
                                                  float* __restrict__ out) {
  const int bid = blockIdx.x;
  const int tk = (bid & 7) * (TT / 8) + (bid >> 3);   // XCD-chunked token order
  const int b = tk >> 9;
  const int l = tk & 511;
  const int base = b * RB;
  const int e4 = threadIdx.x;                // 0..191 u16x4 chunks
  const u16x4* R4 = (const u16x4*)R;
  const f32x4 bb = ((const f32x4*)bias)[e4];
  const int2* sp = (const int2*)(span + ((size_t)b * SS + (size_t)l * MW) * 2);
  f32x4* out4 = (f32x4*)out + ((size_t)b * SS + (size_t)l * MW) * 192 + e4;

#pragma unroll 4
  for (int wdx = 0; wdx < MW; ++wdx) {
    const int2 se = sp[wdx];
    u16x4 pe = R4[(size_t)(base + se.y + 1) * 192 + e4];   // R[end]
    u16x4 mq = R4[(size_t)(base + se.x) * 192 + e4];       // R[start-1]
    f32x4 r;
#pragma unroll
    for (int j = 0; j < 4; ++j) {
      float x = h2f(pe[j]) - h2f(mq[j]) + bb[j];
      r[j] = fmaxf(x, 0.f);
    }
    out4[(size_t)wdx * 192] = r;
  }
}

// ---------- naive fallback (only if ws too small) ----------
__global__ __launch_bounds__(256) void naive_k(const float* __restrict__ h,
                                               const int* __restrict__ span,
                                               const float* __restrict__ W,
                                               const float* __restrict__ bias,
                                               const float* __restrict__ ss,
                                               const float* __restrict__ es,
                                               float* __restrict__ out) {
  int bs = blockIdx.x;
  int b = bs / SS;
  int start = span[(size_t)bs * 2 + 0];
  int end   = span[(size_t)bs * 2 + 1];
  __shared__ float rep[DD];
  const float* hb = h + (size_t)b * LLEN * DD;
  for (int k = threadIdx.x; k < HH; k += blockDim.x) {
    float fs = (start == 0) ? ss[k] : hb[(size_t)(start - 1) * DD + k];
    rep[k] = hb[(size_t)end * DD + k] - fs;
    float bstart = (end + 1 >= LLEN) ? es[k] : hb[(size_t)(end + 1) * DD + HH + k];
    rep[HH + k] = bstart - hb[(size_t)start * DD + HH + k];
  }
  __syncthreads();
  for (int e = threadIdx.x; e < DD; e += blockDim.x) {
    const float* w = W + (size_t)e * DD;
    float acc = bias[e];
    for (int k = 0; k < DD; k += 4) {
      acc += rep[k] * w[k] + rep[k + 1] * w[k + 1] + rep[k + 2] * w[k + 2] + rep[k + 3] * w[k + 3];
    }
    out[(size_t)bs * DD + e] = fmaxf(acc, 0.f);
  }
}

extern "C" void kernel_launch(void* const* d_in, const int* in_sizes, int n_in,
                              void* d_out, int out_size, void* d_ws, size_t ws_size,
                              hipStream_t stream) {
  const float* h  = (const float*)d_in[0];
  const int* span = (const int*)d_in[1];
  const float* W  = (const float*)d_in[2];
  const float* bias = (const float*)d_in[3];
  const float* ss = (const float*)d_in[4];
  const float* es = (const float*)d_in[5];
  float* out = (float*)d_out;

  const size_t szX = (size_t)MX * DD * sizeof(unsigned short);    // 6.49 MB
  const size_t szW = (size_t)DD * DD * sizeof(unsigned short);    // 1.18 MB
  const size_t szR = (size_t)MX * DD * sizeof(unsigned short);    // 6.49 MB
  const size_t need = szX + szW + szR;                            // ~14.2 MB

  if (ws_size < need) {
    naive_k<<<NB * SS, 256, 0, stream>>>(h, span, W, bias, ss, es, out);
    return;
  }

  char* ws = (char*)d_ws;
  unsigned short* X  = (unsigned short*)ws;                // [MX][DD] fp16
  unsigned short* Wp = X + (size_t)MX * DD;                // [DD][DD] fp16
  unsigned short* R  = Wp + (size_t)DD * DD;               // [MX][DD] fp16

  prep_k<<<PREP_BLOCKS, 256, 0, stream>>>(h, W, ss, es, X, Wp);
  gemm_k<<<528, 256, 0, stream>>>(X, Wp, R);
  assemble_k<<<TT, 192, 0, stream>>>(span, R, bias, out);
}

// Round 13
// 48.876 us; speedup vs baseline: 1.0627x; 1.0627x over previous
//
#include <hip/hip_runtime.h>

typedef __attribute__((ext_vector_type(4))) float f32x4;
typedef __attribute__((ext_vector_type(8))) _Float16 f16x8;
typedef __attribute__((ext_vector_type(4))) unsigned short u16x4;

#define NB 8
#define LLEN 512
#define DD 768
#define MW 12
#define HH 384
#define TT (NB * LLEN)      // 4096 tokens
#define SS (LLEN * MW)      // 6144 spans per batch
#define RB 528              // X rows per batch (513 used: t=-1..511, rest pad)
#define MX (NB * RB)        // 4224 X rows

#define BT 32               // tokens per fused block
#define BE 128              // e-slice per fused block
#define WR 48               // R-window rows (44 used: t in [T0-1, T0+42])
#define PR 136              // R-tile LDS pitch in fp16 (272 B: 4-bank shift per row)

#define PREPX_BLOCKS ((MX * 192) / 256)   // 3168
#define PREPW_BLOCKS ((DD * 192) / 256)   // 576
#define PREP_BLOCKS (PREPX_BLOCKS + PREPW_BLOCKS)

// ---------- helpers ----------
__device__ __forceinline__ unsigned short f2h(float x) {
  _Float16 h = (_Float16)x;               // RNE
  return __builtin_bit_cast(unsigned short, h);
}
__device__ __forceinline__ float h2f(unsigned short u) {
  return (float)__builtin_bit_cast(_Float16, u);
}
__device__ __forceinline__ void gload_lds16(const void* g, void* l) {
  __builtin_amdgcn_global_load_lds(
      (const __attribute__((address_space(1))) unsigned int*)g,
      (__attribute__((address_space(3))) unsigned int*)l, 16, 0, 0);
}

// ---------- prep ----------
// X[b*RB + t + 1][0:384]   = fwd[b][t]   (ss at t==-1, clamped past 511)
// X[b*RB + t + 1][384:768] = bwd[b][t+1] (es at t>=511)
// Wp[e][k] = fp16(W[e][k])
__global__ __launch_bounds__(256) void prep_k(const float* __restrict__ h,
                                              const float* __restrict__ W,
                                              const float* __restrict__ ss,
                                              const float* __restrict__ es,
                                              unsigned short* __restrict__ X,
                                              unsigned short* __restrict__ Wp) {
  int bid = blockIdx.x;
  if (bid < PREPX_BLOCKS) {
    int idx = bid * 256 + threadIdx.x;        // over MX*192 u16x4 chunks
    int r = idx / 192;
    int c = (idx - r * 192) * 4;
    int b = r / RB;
    int t = r - b * RB - 1;                   // -1..526
    const float* src;
    if (c < HH) {
      src = (t == -1) ? (ss + c) : (h + ((size_t)b * LLEN + min(t, LLEN - 1)) * DD + c);
    } else {
      src = (t >= LLEN - 1) ? (es + (c - HH))
                            : (h + ((size_t)b * LLEN + (t + 1)) * DD + c);
    }
    f32x4 f = *(const f32x4*)src;
    u16x4 v;
#pragma unroll
    for (int j = 0; j < 4; ++j) v[j] = f2h(f[j]);
    *(u16x4*)(X + (size_t)r * DD + c) = v;
  } else {
    int idx = (bid - PREPX_BLOCKS) * 256 + threadIdx.x;  // over DD*192 chunks
    int e = idx / 192;
    int c = (idx - e * 192) * 4;
    f32x4 f = *(const f32x4*)(W + (size_t)e * DD + c);
    u16x4 v;
#pragma unroll
    for (int j = 0; j < 4; ++j) v[j] = f2h(f[j]);
    *(u16x4*)(Wp + (size_t)e * DD + c) = v;
  }
}

// ---------- fused telescoped GEMM + assemble ----------
// Per block: batch b, tokens [T0, T0+31], e-slice [E0, E0+128).
// Phase 1: R-window GEMM, M=48 (X rows b*RB+T0 .. +47), N=128, K=768.
// Phase 2: acc -> fp16 R tile in LDS (union over dead staging).
// Phase 3: out[l,w] = relu(R[end] - R[start-1] + bias), 2 LDS gathers/row.
// Grid 768 = 6ec x 128(g); 3 blocks/CU ALL CO-RESIDENT -> cross-block phase
// overlap on each CU (GEMM of one block hides under another's write stream).
// bid%8 = g%8: a window's 6 e-siblings share an XCD; per-XCD set ~2.4 MB L2.
__global__ __launch_bounds__(256) void fused_k(const unsigned short* __restrict__ X,
                                               const unsigned short* __restrict__ Wp,
                                               const int* __restrict__ span,
                                               const float* __restrict__ bias,
                                               float* __restrict__ out) {
  __shared__ char lds[WR * 128 + BE * 128];   // 22528 B staging / R-tile union
  __shared__ int2 spans[BT * MW];             // 3072 B

  const int bid = blockIdx.x;
  const int g = ((bid >> 3) / 6) * 8 + (bid & 7);   // window id 0..127
  const int ec = (bid >> 3) % 6;
  const int b = g >> 4;
  const int T0 = (g & 15) * BT;
  const int E0 = ec * BE;

  const int tid = threadIdx.x;
  const int lane = tid & 63;
  const int wc = tid >> 6;                 // wave -> 32-col slice of N=128
  const int l16 = lane & 15, l4 = lane >> 4;

  // stage this block's 384 spans
  {
    const int2* sp = (const int2*)span + (size_t)b * SS + (size_t)T0 * MW;
    for (int s = tid; s < BT * MW; s += 256) spans[s] = sp[s];
  }

  char* As = lds;                          // [48][128B]   X window slice
  char* Bs = lds + WR * 128;               // [128][128B]  Wp slice

  const size_t xbase = (size_t)b * RB + T0;   // X row of window row 0 (t=T0-1)
  const char* Xb = (const char*)X;
  const char* Wb = (const char*)Wp;

  f32x4 acc[3][2] = {};

  for (int kc = 0; kc < DD; kc += 64) {
    // A: 48 rows x 128 B = 6144 B (1.5 rounds of 256x16B)
    {
      int o = tid * 16;
      int rr = o >> 7, cb = o & 127;
      gload_lds16(Xb + ((xbase + rr) * DD + kc) * 2 + cb, As + o);
    }
    if (tid < 128) {
      int o = 4096 + tid * 16;
      int rr = o >> 7, cb = o & 127;
      gload_lds16(Xb + ((xbase + rr) * DD + kc) * 2 + cb, As + o);
    }
    // B: 128 rows x 128 B = 16384 B (4 rounds)
#pragma unroll
    for (int r = 0; r < 4; ++r) {
      int o = (r * 256 + tid) * 16;
      int rr = o >> 7, cb = o & 127;
      gload_lds16(Wb + ((size_t)(E0 + rr) * DD + kc) * 2 + cb, Bs + o);
    }
    __syncthreads();

    f16x8 af[2][3], bf[2][2];
#pragma unroll
    for (int ks = 0; ks < 2; ++ks)
#pragma unroll
      for (int m = 0; m < 3; ++m)
        af[ks][m] = *(const f16x8*)(As + (m * 16 + l16) * 128 + ks * 64 + l4 * 16);
#pragma unroll
    for (int ks = 0; ks < 2; ++ks)
#pragma unroll
      for (int n = 0; n < 2; ++n)
        bf[ks][n] = *(const f16x8*)(Bs + (wc * 32 + n * 16 + l16) * 128 + ks * 64 + l4 * 16);

#pragma unroll
    for (int m = 0; m < 3; ++m)
#pragma unroll
      for (int n = 0; n < 2; ++n) {
        acc[m][n] = __builtin_amdgcn_mfma_f32_16x16x32_f16(af[0][m], bf[0][n], acc[m][n], 0, 0, 0);
        acc[m][n] = __builtin_amdgcn_mfma_f32_16x16x32_f16(af[1][m], bf[1][n], acc[m][n], 0, 0, 0);
      }
    __syncthreads();                       // staging reusable / dead after last iter
  }

  // Phase 2: acc -> fp16 R tile (unions over dead staging)
  unsigned short* Rt = (unsigned short*)lds;   // [48][PR]; row rr = R[T0-1+rr]
#pragma unroll
  for (int m = 0; m < 3; ++m) {
    int row = m * 16 + l4 * 4;
#pragma unroll
    for (int n = 0; n < 2; ++n) {
      int col = wc * 32 + n * 16 + l16;
#pragma unroll
      for (int r = 0; r < 4; ++r)
        Rt[(row + r) * PR + col] = f2h(acc[m][n][r]);
    }
  }
  __syncthreads();

  // Phase 3: out[b, (T0+l)*12+w, E0:E0+128] = relu(R[end] - R[start-1] + b)
  const u16x4* R4 = (const u16x4*)Rt;      // row pitch PR/4 = 34
  const f32x4* bias4 = (const f32x4*)bias + (E0 >> 2);
  f32x4* out4 = (f32x4*)out + ((size_t)b * SS + (size_t)T0 * MW) * (DD / 4) + (E0 >> 2);

  const int e4 = tid & 31;                 // 32 u16x4 chunks per 128-e slice
  int lw = tid >> 5;                       // token-width row, +8 per iter
  const f32x4 bb = bias4[e4];
#pragma unroll 4
  for (int it = 0; it < (BT * MW) / 8; ++it) {   // 48 iters
    const int2 se = spans[lw];
    u16x4 pe = R4[(se.y - T0 + 1) * 34 + e4];    // R[end]
    u16x4 mq = R4[(se.x - T0) * 34 + e4];        // R[start-1]
    f32x4 r;
#pragma unroll
    for (int j = 0; j < 4; ++j) {
      float x = h2f(pe[j]) - h2f(mq[j]) + bb[j];
      r[j] = fmaxf(x, 0.f);
    }
    out4[(size_t)lw * (DD / 4) + e4] = r;
    lw += 8;
  }
}

// ---------- naive fallback (only if ws too small) ----------
__global__ __launch_bounds__(256) void naive_k(const float* __restrict__ h,
                                               const int* __restrict__ span,
                                               const float* __restrict__ W,
                                               const float* __restrict__ bias,
                                               const float* __restrict__ ss,
                                               const float* __restrict__ es,
                                               float* __restrict__ out) {
  int bs = blockIdx.x;
  int b = bs / SS;
  int start = span[(size_t)bs * 2 + 0];
  int end   = span[(size_t)bs * 2 + 1];
  __shared__ float rep[DD];
  const float* hb = h + (size_t)b * LLEN * DD;
  for (int k = threadIdx.x; k < HH; k += blockDim.x) {
    float fs = (start == 0) ? ss[k] : hb[(size_t)(start - 1) * DD + k];
    rep[k] = hb[(size_t)end * DD + k] - fs;
    float bstart = (end + 1 >= LLEN) ? es[k] : hb[(size_t)(end + 1) * DD + HH + k];
    rep[HH + k] = bstart - hb[(size_t)start * DD + HH + k];
  }
  __syncthreads();
  for (int e = threadIdx.x; e < DD; e += blockDim.x) {
    const float* w = W + (size_t)e * DD;
    float acc = bias[e];
    for (int k = 0; k < DD; k += 4) {
      acc += rep[k] * w[k] + rep[k + 1] * w[k + 1] + rep[k + 2] * w[k + 2] + rep[k + 3] * w[k + 3];
    }
    out[(size_t)bs * DD + e] = fmaxf(acc, 0.f);
  }
}

extern "C" void kernel_launch(void* const* d_in, const int* in_sizes, int n_in,
                              void* d_out, int out_size, void* d_ws, size_t ws_size,
                              hipStream_t stream) {
  const float* h  = (const float*)d_in[0];
  const int* span = (const int*)d_in[1];
  const float* W  = (const float*)d_in[2];
  const float* bias = (const float*)d_in[3];
  const float* ss = (const float*)d_in[4];
  const float* es = (const float*)d_in[5];
  float* out = (float*)d_out;

  const size_t szX = (size_t)MX * DD * sizeof(unsigned short);    // 6.49 MB
  const size_t szW = (size_t)DD * DD * sizeof(unsigned short);    // 1.18 MB
  const size_t need = szX + szW;                                  // ~7.7 MB

  if (ws_size < need) {
    naive_k<<<NB * SS, 256, 0, stream>>>(h, span, W, bias, ss, es, out);
    return;
  }

  char* ws = (char*)d_ws;
  unsigned short* X  = (unsigned short*)ws;                // [MX][DD] fp16
  unsigned short* Wp = X + (size_t)MX * DD;                // [DD][DD] fp16

  prep_k<<<PREP_BLOCKS, 256, 0, stream>>>(h, W, ss, es, X, Wp);
  fused_k<<<768, 256, 0, stream>>>(X, Wp, span, bias, out);
}